// Round 1
// baseline (1586.282 us; speedup 1.0000x reference)
//
#include <hip/hip_runtime.h>
#include <hip/hip_bf16.h>

// GRU, 16 steps, B=4096, H=1024. x==h for steps>=1 -> combined gate weights.
// Gate GEMM: Z[B,4H] = h_bf16 @ Wc[4H,H]^T  (Wc rows: r=Wih_r+Whh_r, z=Wih_z+Whh_z, ni=Wih_n, nh=Whh_n)
// Elementwise: r,z,n -> h_new (f32 master copy), emit h_bf16 + relu(h)_bf16
// Out GEMM: out_t[B,H] = relu(h)_bf16 @ Wout_bf16^T + b_out

#define H_DIM 1024
#define BATCH_N 4096
#define NSTEPS 16
#define K4 (4 * H_DIM)

typedef __bf16 bf16_t;
typedef __bf16 bf16x8 __attribute__((ext_vector_type(8)));
typedef __bf16 bf16x4 __attribute__((ext_vector_type(4)));
typedef float f32x4 __attribute__((ext_vector_type(4)));

// ---------------- prep kernels ----------------

__global__ __launch_bounds__(256) void prep_weights(
    const float* __restrict__ Wih, const float* __restrict__ Whh,
    const float* __restrict__ bih, const float* __restrict__ bhh,
    const float* __restrict__ Wout,
    bf16_t* __restrict__ Wc0, bf16_t* __restrict__ Wc,
    bf16_t* __restrict__ Wob, float* __restrict__ biasc)
{
    const int stride = gridDim.x * blockDim.x;
    const int idx = blockIdx.x * blockDim.x + threadIdx.x;

    // combined gate weights (4H x H)
    const int total = K4 * H_DIM;
    for (int i = idx; i < total; i += stride) {
        const int row = i >> 10;           // / H_DIM
        const int col = i & (H_DIM - 1);
        const int gate = row >> 10;        // 0=r,1=z,2=ni,3=nh
        const int r0 = row & (H_DIM - 1);
        float vc, v0;
        if (gate == 0) {
            float a = Wih[(size_t)r0 * H_DIM + col];
            float b = Whh[(size_t)r0 * H_DIM + col];
            vc = a + b; v0 = b;
        } else if (gate == 1) {
            float a = Wih[(size_t)(H_DIM + r0) * H_DIM + col];
            float b = Whh[(size_t)(H_DIM + r0) * H_DIM + col];
            vc = a + b; v0 = b;
        } else if (gate == 2) {
            vc = Wih[(size_t)(2 * H_DIM + r0) * H_DIM + col];
            v0 = 0.0f;   // step 0: x = 0 -> no i_n contribution
        } else {
            float b = Whh[(size_t)(2 * H_DIM + r0) * H_DIM + col];
            vc = b; v0 = b;
        }
        Wc[i]  = (bf16_t)vc;
        Wc0[i] = (bf16_t)v0;
    }
    // W_out -> bf16
    for (int i = idx; i < H_DIM * H_DIM; i += stride)
        Wob[i] = (bf16_t)Wout[i];
    // combined bias (4H)
    for (int i = idx; i < K4; i += stride) {
        const int gate = i >> 10;
        const int r0 = i & (H_DIM - 1);
        float v;
        if (gate == 0)      v = bih[r0] + bhh[r0];
        else if (gate == 1) v = bih[H_DIM + r0] + bhh[H_DIM + r0];
        else if (gate == 2) v = bih[2 * H_DIM + r0];
        else                v = bhh[2 * H_DIM + r0];
        biasc[i] = v;
    }
}

__global__ __launch_bounds__(256) void prep_h(
    const float* __restrict__ h0, float* __restrict__ h, bf16_t* __restrict__ hb)
{
    const int stride = gridDim.x * blockDim.x;
    for (int i = blockIdx.x * blockDim.x + threadIdx.x; i < BATCH_N * H_DIM; i += stride) {
        float v = h0[i];
        h[i] = v;
        hb[i] = (bf16_t)v;
    }
}

// ---------------- GEMM: C[M,N] = A[M,K] @ Bm[N,K]^T (+bias) ----------------
// m97 structure: 128x128 tile, BK=64, 4 waves (2x2), 16x16x32 bf16 MFMA,
// global_load_lds width-16 staging into linear LDS.

__global__ __launch_bounds__(256, 2) void gemm_bt_128(
    const bf16_t* __restrict__ A, const bf16_t* __restrict__ Bm,
    float* __restrict__ C, int M, int N, int K,
    const float* __restrict__ bias)
{
    __shared__ bf16_t la[128 * 64];
    __shared__ bf16_t lb[128 * 64];

    const int tid = threadIdx.x;
    const int l = tid & 63;
    const int w = tid >> 6;
    const int brow = blockIdx.y * 128;
    const int bcol = blockIdx.x * 128;
    const int wr = w >> 1, wc = w & 1;

    f32x4 acc[4][4];
    const f32x4 zero = {0.f, 0.f, 0.f, 0.f};
#pragma unroll
    for (int m = 0; m < 4; ++m)
#pragma unroll
        for (int n = 0; n < 4; ++n) acc[m][n] = zero;

    const int lrow = l >> 3;          // row within 8-row chunk
    const int lcol = (l & 7) * 8;     // bf16 col offset (16B per lane)

    const int nk = K >> 6;
    for (int kt = 0; kt < nk; ++kt) {
        __syncthreads();
        const int k0 = kt * 64;
#pragma unroll
        for (int i = 0; i < 4; ++i) {
            const int chunk = w * 32 + i * 8;   // 8 rows per wave-iteration
            const bf16_t* ga = A + (size_t)(brow + chunk + lrow) * K + k0 + lcol;
            const bf16_t* gb = Bm + (size_t)(bcol + chunk + lrow) * K + k0 + lcol;
            __builtin_amdgcn_global_load_lds(
                (const __attribute__((address_space(1))) void*)ga,
                (__attribute__((address_space(3))) void*)(la + chunk * 64), 16, 0, 0);
            __builtin_amdgcn_global_load_lds(
                (const __attribute__((address_space(1))) void*)gb,
                (__attribute__((address_space(3))) void*)(lb + chunk * 64), 16, 0, 0);
        }
        __syncthreads();   // drains vmcnt before compute

#pragma unroll
        for (int kk = 0; kk < 2; ++kk) {
            bf16x8 af[4], bfr[4];
#pragma unroll
            for (int m = 0; m < 4; ++m)
                af[m] = *(const bf16x8*)&la[(wr * 64 + m * 16 + (l & 15)) * 64 + kk * 32 + (l >> 4) * 8];
#pragma unroll
            for (int n = 0; n < 4; ++n)
                bfr[n] = *(const bf16x8*)&lb[(wc * 64 + n * 16 + (l & 15)) * 64 + kk * 32 + (l >> 4) * 8];
#pragma unroll
            for (int m = 0; m < 4; ++m)
#pragma unroll
                for (int n = 0; n < 4; ++n)
                    acc[m][n] = __builtin_amdgcn_mfma_f32_16x16x32_bf16(af[m], bfr[n], acc[m][n], 0, 0, 0);
        }
    }

    // epilogue: C/D layout col=lane&15, row=(lane>>4)*4+j  [verified m89/m91]
    const int crow0 = brow + wr * 64 + ((l >> 4) << 2);
    const int ccol0 = bcol + wc * 64 + (l & 15);
#pragma unroll
    for (int m = 0; m < 4; ++m) {
#pragma unroll
        for (int n = 0; n < 4; ++n) {
            const int col = ccol0 + n * 16;
            const float badd = bias ? bias[col] : 0.0f;
#pragma unroll
            for (int j = 0; j < 4; ++j) {
                const int row = crow0 + m * 16 + j;
                C[(size_t)row * N + col] = acc[m][n][j] + badd;
            }
        }
    }
}

// ---------------- GRU elementwise ----------------

__device__ __forceinline__ float sigm(float x) { return 1.0f / (1.0f + __expf(-x)); }

__global__ __launch_bounds__(256) void gru_elem(
    const float* __restrict__ Z, const float* __restrict__ biasc,
    float* __restrict__ h, bf16_t* __restrict__ hb, bf16_t* __restrict__ hr)
{
    const int idx = blockIdx.x * blockDim.x + threadIdx.x;   // one per 4 elems
    const int row = idx >> 8;             // H/4 = 256 vec4 per row
    const int j4 = (idx & 255) * 4;

    const size_t zb = (size_t)row * K4 + j4;
    f32x4 vr = *(const f32x4*)&Z[zb];
    f32x4 vz = *(const f32x4*)&Z[zb + H_DIM];
    f32x4 vi = *(const f32x4*)&Z[zb + 2 * H_DIM];
    f32x4 vh = *(const f32x4*)&Z[zb + 3 * H_DIM];
    f32x4 br = *(const f32x4*)&biasc[j4];
    f32x4 bz = *(const f32x4*)&biasc[H_DIM + j4];
    f32x4 bi = *(const f32x4*)&biasc[2 * H_DIM + j4];
    f32x4 bh = *(const f32x4*)&biasc[3 * H_DIM + j4];
    const size_t hbase = (size_t)row * H_DIM + j4;
    f32x4 hold = *(const f32x4*)&h[hbase];

    f32x4 hnew;
    bf16x4 hbv, hrv;
#pragma unroll
    for (int k = 0; k < 4; ++k) {
        float r = sigm(vr[k] + br[k]);
        float z = sigm(vz[k] + bz[k]);
        float a = vi[k] + bi[k] + r * (vh[k] + bh[k]);
        a = fminf(fmaxf(a, -30.f), 30.f);
        float e = __expf(-2.f * a);
        float n = (1.f - e) / (1.f + e);
        float hn = (1.f - z) * n + z * hold[k];
        hnew[k] = hn;
        hbv[k] = (bf16_t)hn;
        hrv[k] = (bf16_t)fmaxf(hn, 0.f);
    }
    *(f32x4*)&h[hbase] = hnew;
    *(bf16x4*)&hb[hbase] = hbv;
    *(bf16x4*)&hr[hbase] = hrv;
}

// ---------------- launch ----------------

extern "C" void kernel_launch(void* const* d_in, const int* in_sizes, int n_in,
                              void* d_out, int out_size, void* d_ws, size_t ws_size,
                              hipStream_t stream)
{
    const float* hidden = (const float*)d_in[0];
    const float* Wih = (const float*)d_in[1];
    const float* Whh = (const float*)d_in[2];
    const float* bih = (const float*)d_in[3];
    const float* bhh = (const float*)d_in[4];
    const float* Wout = (const float*)d_in[5];
    const float* bout = (const float*)d_in[6];
    float* out = (float*)d_out;

    char* ws = (char*)d_ws;
    size_t off = 0;
    bf16_t* Wc0 = (bf16_t*)(ws + off); off += (size_t)K4 * H_DIM * 2;        // 8 MB
    bf16_t* Wc  = (bf16_t*)(ws + off); off += (size_t)K4 * H_DIM * 2;        // 8 MB
    bf16_t* Wob = (bf16_t*)(ws + off); off += (size_t)H_DIM * H_DIM * 2;     // 2 MB
    float*  biasc = (float*)(ws + off); off += (size_t)K4 * 4;               // 16 KB
    float*  hf = (float*)(ws + off); off += (size_t)BATCH_N * H_DIM * 4;     // 16 MB
    bf16_t* hb = (bf16_t*)(ws + off); off += (size_t)BATCH_N * H_DIM * 2;    // 8 MB
    bf16_t* hr = (bf16_t*)(ws + off); off += (size_t)BATCH_N * H_DIM * 2;    // 8 MB
    float*  Zb = (float*)(ws + off); off += (size_t)BATCH_N * K4 * 4;        // 64 MB
    (void)ws_size; (void)in_sizes; (void)n_in; (void)out_size;

    prep_weights<<<1024, 256, 0, stream>>>(Wih, Whh, bih, bhh, Wout, Wc0, Wc, Wob, biasc);
    prep_h<<<2048, 256, 0, stream>>>(hidden, hf, hb);

    for (int t = 0; t < NSTEPS; ++t) {
        // Z = h @ Wc^T   (M=4096, N=4096, K=1024)
        gemm_bt_128<<<dim3(K4 / 128, BATCH_N / 128), 256, 0, stream>>>(
            hb, (t == 0) ? Wc0 : Wc, Zb, BATCH_N, K4, H_DIM, nullptr);
        // gates -> h_new
        gru_elem<<<(BATCH_N * H_DIM / 4) / 256, 256, 0, stream>>>(Zb, biasc, hf, hb, hr);
        // out_t = relu(h) @ Wout^T + b_out   (M=4096, N=1024, K=1024)
        gemm_bt_128<<<dim3(H_DIM / 128, BATCH_N / 128), 256, 0, stream>>>(
            hr, Wob, out + (size_t)t * BATCH_N * H_DIM, BATCH_N, H_DIM, H_DIM, bout);
    }
}

// Round 2
// 1063.968 us; speedup vs baseline: 1.4909x; 1.4909x over previous
//
#include <hip/hip_runtime.h>
#include <hip/hip_bf16.h>

// GRU, 16 steps, B=4096, H=1024. x==h for steps>=1 -> combined gate weights.
// Gate GEMM (fused): Z = h_bf16 @ Wc'[4H,H]^T with gate-interleaved rows so the
//   MFMA epilogue holds all 4 gates of one h-col per thread -> h_new in-register.
// Out GEMM: batched over all 16 steps if ws_size permits.

#define H_DIM 1024
#define BATCH_N 4096
#define NSTEPS 16
#define K4 (4 * H_DIM)

typedef __bf16 bf16_t;
typedef __bf16 bf16x8 __attribute__((ext_vector_type(8)));
typedef __bf16 bf16x4 __attribute__((ext_vector_type(4)));
typedef float f32x4 __attribute__((ext_vector_type(4)));

__device__ __forceinline__ float sigm(float x) { return 1.0f / (1.0f + __expf(-x)); }

// ---------------- prep kernels ----------------
// Wc' row c' (0..4095): gate g=(c'>>4)&3, h-row hc=((c'>>6)<<4)|(c'&15)
//   g: 0=r (Wih+Whh), 1=z (Wih+Whh), 2=i_n (Wih), 3=h_n (Whh)
// Wc0: step-0 variant (x=0 -> drop Wih contributions).

__global__ __launch_bounds__(256) void prep_weights(
    const float* __restrict__ Wih, const float* __restrict__ Whh,
    const float* __restrict__ bih, const float* __restrict__ bhh,
    const float* __restrict__ Wout,
    bf16_t* __restrict__ Wc0, bf16_t* __restrict__ Wc,
    bf16_t* __restrict__ Wob, float* __restrict__ biasc)
{
    const int stride = gridDim.x * blockDim.x;
    const int idx = blockIdx.x * blockDim.x + threadIdx.x;

    const int total = K4 * H_DIM;
    for (int i = idx; i < total; i += stride) {
        const int c2 = i >> 10;            // new (permuted) row
        const int col = i & (H_DIM - 1);
        const int gate = (c2 >> 4) & 3;
        const int hc = ((c2 >> 6) << 4) | (c2 & 15);
        float vc, v0;
        if (gate == 0) {
            float a = Wih[(size_t)hc * H_DIM + col];
            float b = Whh[(size_t)hc * H_DIM + col];
            vc = a + b; v0 = b;
        } else if (gate == 1) {
            float a = Wih[(size_t)(H_DIM + hc) * H_DIM + col];
            float b = Whh[(size_t)(H_DIM + hc) * H_DIM + col];
            vc = a + b; v0 = b;
        } else if (gate == 2) {
            vc = Wih[(size_t)(2 * H_DIM + hc) * H_DIM + col];
            v0 = 0.0f;   // step 0: x = 0
        } else {
            float b = Whh[(size_t)(2 * H_DIM + hc) * H_DIM + col];
            vc = b; v0 = b;
        }
        Wc[i]  = (bf16_t)vc;
        Wc0[i] = (bf16_t)v0;
    }
    for (int i = idx; i < H_DIM * H_DIM; i += stride)
        Wob[i] = (bf16_t)Wout[i];
    // biasc in gate-major [4][H]: r=bih+bhh, z=bih+bhh, i_n=bih, h_n=bhh
    for (int i = idx; i < K4; i += stride) {
        const int gate = i >> 10;
        const int hc = i & (H_DIM - 1);
        float v;
        if (gate == 0)      v = bih[hc] + bhh[hc];
        else if (gate == 1) v = bih[H_DIM + hc] + bhh[H_DIM + hc];
        else if (gate == 2) v = bih[2 * H_DIM + hc];
        else                v = bhh[2 * H_DIM + hc];
        biasc[i] = v;
    }
}

__global__ __launch_bounds__(256) void prep_h(
    const float* __restrict__ h0, float* __restrict__ h, bf16_t* __restrict__ hb)
{
    const int stride = gridDim.x * blockDim.x;
    for (int i = blockIdx.x * blockDim.x + threadIdx.x; i < BATCH_N * H_DIM; i += stride) {
        float v = h0[i];
        h[i] = v;
        hb[i] = (bf16_t)v;
    }
}

// ---------------- GEMM: 128x128 tile, BK=64, 4 waves, global_load_lds ----------------
// FUSED=1: gate GEMM + GRU epilogue (N must be 4096, gate-interleaved B).
// FUSED=0: C[M,N] = A@Bm^T + bias.

template <bool FUSED>
__global__ __launch_bounds__(256, 2) void gemm_bt(
    const bf16_t* __restrict__ A, const bf16_t* __restrict__ Bm,
    int M, int N, int K,
    float* __restrict__ C, const float* __restrict__ bias,
    const float* __restrict__ biasc, float* __restrict__ hf,
    bf16_t* __restrict__ hbout, bf16_t* __restrict__ hr)
{
    __shared__ bf16_t la[128 * 64];
    __shared__ bf16_t lb[128 * 64];

    const int tid = threadIdx.x;
    const int l = tid & 63;
    const int w = tid >> 6;
    const int brow = blockIdx.y * 128;
    const int bcol = blockIdx.x * 128;
    const int wr = w >> 1, wc = w & 1;

    f32x4 acc[4][4];
    const f32x4 zero = {0.f, 0.f, 0.f, 0.f};
#pragma unroll
    for (int m = 0; m < 4; ++m)
#pragma unroll
        for (int n = 0; n < 4; ++n) acc[m][n] = zero;

    const int lrow = l >> 3;
    const int lcol = (l & 7) * 8;

    const int nk = K >> 6;
    for (int kt = 0; kt < nk; ++kt) {
        __syncthreads();
        const int k0 = kt * 64;
#pragma unroll
        for (int i = 0; i < 4; ++i) {
            const int chunk = w * 32 + i * 8;
            const bf16_t* ga = A + (size_t)(brow + chunk + lrow) * K + k0 + lcol;
            const bf16_t* gb = Bm + (size_t)(bcol + chunk + lrow) * K + k0 + lcol;
            __builtin_amdgcn_global_load_lds(
                (const __attribute__((address_space(1))) void*)ga,
                (__attribute__((address_space(3))) void*)(la + chunk * 64), 16, 0, 0);
            __builtin_amdgcn_global_load_lds(
                (const __attribute__((address_space(1))) void*)gb,
                (__attribute__((address_space(3))) void*)(lb + chunk * 64), 16, 0, 0);
        }
        __syncthreads();

#pragma unroll
        for (int kk = 0; kk < 2; ++kk) {
            bf16x8 af[4], bfr[4];
#pragma unroll
            for (int m = 0; m < 4; ++m)
                af[m] = *(const bf16x8*)&la[(wr * 64 + m * 16 + (l & 15)) * 64 + kk * 32 + (l >> 4) * 8];
#pragma unroll
            for (int n = 0; n < 4; ++n)
                bfr[n] = *(const bf16x8*)&lb[(wc * 64 + n * 16 + (l & 15)) * 64 + kk * 32 + (l >> 4) * 8];
#pragma unroll
            for (int m = 0; m < 4; ++m)
#pragma unroll
                for (int n = 0; n < 4; ++n)
                    acc[m][n] = __builtin_amdgcn_mfma_f32_16x16x32_bf16(af[m], bfr[n], acc[m][n], 0, 0, 0);
        }
    }

    // C/D layout: col = lane&15, row = (lane>>4)*4 + j  [verified m89/m91]
    if constexpr (FUSED) {
        // thread holds gates g=n (r,z,i_n,h_n) of h-col hc, rows crow0+m*16+j
        const int hc = (bcol >> 2) + wc * 16 + (l & 15);
        const float br_ = biasc[hc];
        const float bz_ = biasc[H_DIM + hc];
        const float bi_ = biasc[2 * H_DIM + hc];
        const float bh_ = biasc[3 * H_DIM + hc];
        const int r0 = brow + wr * 64 + ((l >> 4) << 2);
#pragma unroll
        for (int m = 0; m < 4; ++m) {
#pragma unroll
            for (int j = 0; j < 4; ++j) {
                const int row = r0 + m * 16 + j;
                const size_t o = (size_t)row * H_DIM + hc;
                const float hold = hf[o];
                const float r = sigm(acc[m][0][j] + br_);
                const float z = sigm(acc[m][1][j] + bz_);
                float a = acc[m][2][j] + bi_ + r * (acc[m][3][j] + bh_);
                a = fminf(fmaxf(a, -30.f), 30.f);
                const float e = __expf(-2.f * a);
                const float n = (1.f - e) / (1.f + e);
                const float hn = (1.f - z) * n + z * hold;
                hf[o] = hn;
                hbout[o] = (bf16_t)hn;
                hr[o] = (bf16_t)fmaxf(hn, 0.f);
            }
        }
    } else {
        const int crow0 = brow + wr * 64 + ((l >> 4) << 2);
        const int ccol0 = bcol + wc * 64 + (l & 15);
#pragma unroll
        for (int m = 0; m < 4; ++m) {
#pragma unroll
            for (int n = 0; n < 4; ++n) {
                const int col = ccol0 + n * 16;
                const float badd = bias ? bias[col] : 0.0f;
#pragma unroll
                for (int j = 0; j < 4; ++j) {
                    const int row = crow0 + m * 16 + j;
                    C[(size_t)row * N + col] = acc[m][n][j] + badd;
                }
            }
        }
    }
}

// ---------------- launch ----------------

extern "C" void kernel_launch(void* const* d_in, const int* in_sizes, int n_in,
                              void* d_out, int out_size, void* d_ws, size_t ws_size,
                              hipStream_t stream)
{
    const float* hidden = (const float*)d_in[0];
    const float* Wih = (const float*)d_in[1];
    const float* Whh = (const float*)d_in[2];
    const float* bih = (const float*)d_in[3];
    const float* bhh = (const float*)d_in[4];
    const float* Wout = (const float*)d_in[5];
    const float* bout = (const float*)d_in[6];
    float* out = (float*)d_out;
    (void)in_sizes; (void)n_in; (void)out_size;

    char* ws = (char*)d_ws;
    size_t off = 0;
    bf16_t* Wc0 = (bf16_t*)(ws + off); off += (size_t)K4 * H_DIM * 2;        // 8 MB
    bf16_t* Wc  = (bf16_t*)(ws + off); off += (size_t)K4 * H_DIM * 2;        // 8 MB
    bf16_t* Wob = (bf16_t*)(ws + off); off += (size_t)H_DIM * H_DIM * 2;     // 2 MB
    float*  biasc = (float*)(ws + off); off += (size_t)K4 * 4;               // 16 KB
    float*  hf = (float*)(ws + off); off += (size_t)BATCH_N * H_DIM * 4;     // 16 MB
    bf16_t* hbA = (bf16_t*)(ws + off); off += (size_t)BATCH_N * H_DIM * 2;   // 8 MB
    bf16_t* hbB = (bf16_t*)(ws + off); off += (size_t)BATCH_N * H_DIM * 2;   // 8 MB

    const size_t hr_step = (size_t)BATCH_N * H_DIM;     // elems per step
    const size_t need_batched = off + NSTEPS * hr_step * 2;
    const bool batched = (ws_size >= need_batched);
    bf16_t* hr_all = (bf16_t*)(ws + off);               // 128 MB if batched, 8 MB else

    prep_weights<<<1024, 256, 0, stream>>>(Wih, Whh, bih, bhh, Wout, Wc0, Wc, Wob, biasc);
    prep_h<<<2048, 256, 0, stream>>>(hidden, hf, hbA);

    for (int t = 0; t < NSTEPS; ++t) {
        bf16_t* hin  = (t & 1) ? hbB : hbA;
        bf16_t* hout = (t & 1) ? hbA : hbB;
        bf16_t* hr_t = batched ? (hr_all + (size_t)t * hr_step) : hr_all;
        // fused gate GEMM: M=4096, N=4096, K=1024 + GRU epilogue
        gemm_bt<true><<<dim3(K4 / 128, BATCH_N / 128), 256, 0, stream>>>(
            hin, (t == 0) ? Wc0 : Wc, BATCH_N, K4, H_DIM,
            nullptr, nullptr, biasc, hf, hout, hr_t);
        if (!batched) {
            gemm_bt<false><<<dim3(H_DIM / 128, BATCH_N / 128), 256, 0, stream>>>(
                hr_t, Wob, BATCH_N, H_DIM, H_DIM,
                out + (size_t)t * hr_step, bout, nullptr, nullptr, nullptr, nullptr);
        }
    }
    if (batched) {
        // one big out GEMM: M = 16*4096, N = 1024, K = 1024
        gemm_bt<false><<<dim3(H_DIM / 128, (NSTEPS * BATCH_N) / 128), 256, 0, stream>>>(
            hr_all, Wob, NSTEPS * BATCH_N, H_DIM, H_DIM,
            out, bout, nullptr, nullptr, nullptr, nullptr);
    }
}